// Round 7
// baseline (630.488 us; speedup 1.0000x reference)
//
#include <hip/hip_runtime.h>
#include <hip/hip_bf16.h>

#define NN 50000
#define NE 800000
#define HID 64
#define EPSV 1e-5f
#define NBLK 196            // ceil(NN/256)

typedef __attribute__((ext_vector_type(8))) short bf16x8;
typedef __attribute__((ext_vector_type(4))) float f32x4;
typedef __attribute__((ext_vector_type(4))) int int4v;

__device__ __forceinline__ ushort f2b(float f) {
    union { __hip_bfloat16 b; ushort u; } c;
    c.b = __float2bfloat16(f);
    return c.u;
}
__device__ __forceinline__ float b2f(ushort u) {
    return __uint_as_float(((unsigned int)u) << 16);
}

// ---------------- weight f32 -> bf16 prep (edge MLP) ----------------
__global__ void prep_w_kernel(const float* __restrict__ W1, const float* __restrict__ W2,
                              ushort* __restrict__ W1b, ushort* __restrict__ W2b) {
    int i = blockIdx.x * 256 + threadIdx.x;   // 0..32767
    if (i < 16384) W1b[i] = f2b(W1[i]);
    else           W2b[i - 16384] = f2b(W2[i - 16384]);
}

// ---------------- CSR build: count, scan, fill ----------------
__global__ void count_kernel(const int* __restrict__ tgt, int* __restrict__ icnt) {
    int e = blockIdx.x * 256 + threadIdx.x;
    if (e < NE) atomicAdd(&icnt[tgt[e]], 1);
}

__global__ void scan1_kernel(const int* __restrict__ icnt, int* __restrict__ off,
                             int* __restrict__ bsum) {
    __shared__ int s[256];
    const int t = threadIdx.x;
    const int i = blockIdx.x * 256 + t;
    int v = (i < NN) ? icnt[i] : 0;
    s[t] = v;
    __syncthreads();
    for (int d = 1; d < 256; d <<= 1) {
        int x = (t >= d) ? s[t - d] : 0;
        __syncthreads();
        s[t] += x;
        __syncthreads();
    }
    if (i < NN) off[i] = s[t];             // inclusive, block-local
    if (t == 255) bsum[blockIdx.x] = s[255];
}

__global__ void scan2_kernel(const int* __restrict__ bsum, int* __restrict__ bpre) {
    __shared__ int s[256];
    const int t = threadIdx.x;
    int v = (t < NBLK) ? bsum[t] : 0;
    s[t] = v;
    __syncthreads();
    for (int d = 1; d < 256; d <<= 1) {
        int x = (t >= d) ? s[t - d] : 0;
        __syncthreads();
        s[t] += x;
        __syncthreads();
    }
    if (t < NBLK) bpre[t] = s[t] - v;      // exclusive
}

__global__ void scan3_kernel(const int* __restrict__ icnt, const int* __restrict__ bpre,
                             int* __restrict__ off, int* __restrict__ woff) {
    const int i = blockIdx.x * 256 + threadIdx.x;
    if (i < NN) {
        int e = off[i] - icnt[i] + bpre[blockIdx.x];   // exclusive global
        off[i] = e;
        woff[i] = e;
        if (i == NN - 1) off[NN] = NE;
    }
}

__global__ void fill_kernel(const int* __restrict__ src, const int* __restrict__ tgt,
                            int* __restrict__ woff, int* __restrict__ ebuf) {
    int e = blockIdx.x * 256 + threadIdx.x;
    if (e < NE) {
        int p = atomicAdd(&woff[tgt[e]], 1);
        ebuf[p] = src[e];
    }
}

// ---------------- projection GEMM ----------------
// seg0: xb (bf16) = A @ W0.T        seg1: pre = A @ W1s.T + bias1
// seg2: res = A @ W2s.T + bias2 (layer 0 only)
#define PADA 260
#define PADBW 68

__global__ __launch_bounds__(256, 2) void proj_gemm_kernel(
    const float* __restrict__ A, int K,
    const float* __restrict__ W0, const float* __restrict__ W1s,
    const float* __restrict__ W2s,
    const float* __restrict__ bias1, const float* __restrict__ bias2,
    ushort* __restrict__ xb, float* __restrict__ pre, float* __restrict__ res)
{
    __shared__ float At[32 * PADA];
    __shared__ float Bt[32 * PADBW];
    const int tid = threadIdx.x;
    const int seg = blockIdx.y;
    const float* W  = (seg == 0) ? W0 : ((seg == 1) ? W1s : W2s);
    const float* bp = (seg == 1) ? bias1 : ((seg == 2) ? bias2 : nullptr);
    const int n0 = blockIdx.x * 256;
    const int tn = tid & 31, to = tid >> 5;

    float bias[8];
    #pragma unroll
    for (int j = 0; j < 8; j++) bias[j] = bp ? bp[to * 8 + j] : 0.f;
    float acc[8][8];
    #pragma unroll
    for (int i = 0; i < 8; i++)
        #pragma unroll
        for (int j = 0; j < 8; j++) acc[i][j] = bias[j];

    for (int kc = 0; kc < K; kc += 32) {
        {
            const int nb = tid >> 3, k4 = (tid & 7) * 4;
            #pragma unroll
            for (int i = 0; i < 8; i++) {
                int col = nb + 32 * i;
                int n = n0 + col; if (n > NN - 1) n = NN - 1;
                float4 v = *(const float4*)&A[(long)n * K + kc + k4];
                int base = k4 * PADA + col;
                At[base] = v.x; At[base + PADA] = v.y;
                At[base + 2 * PADA] = v.z; At[base + 3 * PADA] = v.w;
            }
            const int oc = tid & 63, k8 = (tid >> 6) * 8;
            float4 w0 = *(const float4*)&W[(long)oc * K + kc + k8];
            float4 w1 = *(const float4*)&W[(long)oc * K + kc + k8 + 4];
            Bt[(k8 + 0) * PADBW + oc] = w0.x; Bt[(k8 + 1) * PADBW + oc] = w0.y;
            Bt[(k8 + 2) * PADBW + oc] = w0.z; Bt[(k8 + 3) * PADBW + oc] = w0.w;
            Bt[(k8 + 4) * PADBW + oc] = w1.x; Bt[(k8 + 5) * PADBW + oc] = w1.y;
            Bt[(k8 + 6) * PADBW + oc] = w1.z; Bt[(k8 + 7) * PADBW + oc] = w1.w;
        }
        __syncthreads();
        #pragma unroll 4
        for (int k = 0; k < 32; k++) {
            float4 a0 = *(const float4*)&At[k * PADA + tn * 4];
            float4 a1 = *(const float4*)&At[k * PADA + 128 + tn * 4];
            float4 b0 = *(const float4*)&Bt[k * PADBW + to * 8];
            float4 b1 = *(const float4*)&Bt[k * PADBW + to * 8 + 4];
            float av[8] = {a0.x, a0.y, a0.z, a0.w, a1.x, a1.y, a1.z, a1.w};
            float bv[8] = {b0.x, b0.y, b0.z, b0.w, b1.x, b1.y, b1.z, b1.w};
            #pragma unroll
            for (int i = 0; i < 8; i++)
                #pragma unroll
                for (int j = 0; j < 8; j++)
                    acc[i][j] = fmaf(av[i], bv[j], acc[i][j]);
        }
        __syncthreads();
    }
    #pragma unroll
    for (int i = 0; i < 8; i++) {
        int n = n0 + ((i < 4) ? (tn * 4 + i) : (128 + tn * 4 + i - 4));
        if (n < NN) {
            if (seg == 0) {
                union { ushort u[8]; int4v v; } pk;
                #pragma unroll
                for (int j = 0; j < 8; j++) pk.u[j] = f2b(acc[i][j]);
                *(int4v*)&xb[(long)n * 64 + to * 8] = pk.v;
            } else {
                float* O = (seg == 1) ? pre : res;
                float* cp = &O[(long)n * 64 + to * 8];
                *(float4*)cp       = make_float4(acc[i][0], acc[i][1], acc[i][2], acc[i][3]);
                *(float4*)(cp + 4) = make_float4(acc[i][4], acc[i][5], acc[i][6], acc[i][7]);
            }
        }
    }
}

// ---------------- gather (mean aggr, bf16 src) + self term + BN stats ----------------
__global__ __launch_bounds__(256) void gather_bn_kernel(
    const int* __restrict__ off, const int* __restrict__ ebuf,
    const ushort* __restrict__ xb,
    float* __restrict__ vbase,
    float* __restrict__ bnsum, float* __restrict__ bnsq)
{
    __shared__ float r1[4][64], r2[4][64];
    const int lane = threadIdx.x & 63;
    const int wid = __builtin_amdgcn_readfirstlane(threadIdx.x >> 6);
    float s = 0.f, q = 0.f;
    for (int n = blockIdx.x * 4 + wid; n < NN; n += gridDim.x * 4) {
        const int a = off[n], b = off[n + 1];
        float a0 = 0.f, a1 = 0.f, a2 = 0.f, a3 = 0.f;
        int p = a;
        for (; p + 4 <= b; p += 4) {
            int s0 = ebuf[p], s1 = ebuf[p + 1], s2 = ebuf[p + 2], s3 = ebuf[p + 3];
            a0 += b2f(xb[(long)s0 * 64 + lane]);
            a1 += b2f(xb[(long)s1 * 64 + lane]);
            a2 += b2f(xb[(long)s2 * 64 + lane]);
            a3 += b2f(xb[(long)s3 * 64 + lane]);
        }
        for (; p < b; ++p) a0 += b2f(xb[(long)ebuf[p] * 64 + lane]);
        float acc = (a0 + a1) + (a2 + a3);
        float v = acc / fmaxf((float)(b - a), 1.f) + vbase[(long)n * 64 + lane];
        vbase[(long)n * 64 + lane] = v;
        s += v; q += v * v;
    }
    r1[wid][lane] = s; r2[wid][lane] = q;
    __syncthreads();
    if (threadIdx.x < 64) {
        s = r1[0][lane] + r1[1][lane] + r1[2][lane] + r1[3][lane];
        q = r2[0][lane] + r2[1][lane] + r2[2][lane] + r2[3][lane];
        atomicAdd(&bnsum[lane], s);
        atomicAdd(&bnsq[lane], q);
    }
}

// ---------------- BN finalize ----------------
__global__ void bnfin_kernel(const float* __restrict__ bnsum, const float* __restrict__ bnsq,
                             const float* __restrict__ g, const float* __restrict__ be,
                             float* __restrict__ scale, float* __restrict__ shift)
{
    int c = threadIdx.x;  // 64
    float inv_n = 1.0f / (float)NN;
    float mu = bnsum[c] * inv_n;
    float var = bnsq[c] * inv_n - mu * mu;
    float rstd = rsqrtf(var + EPSV);
    float sc = g[c] * rstd;
    scale[c] = sc;
    shift[c] = be[c] - mu * sc;
}

// ---------------- BN apply + ReLU + residual ----------------
__global__ void apply_kernel(const float* __restrict__ vbase,
                             const float* __restrict__ resbase,
                             const float* __restrict__ scale, const float* __restrict__ shift,
                             float* __restrict__ h, ushort* hb)
{
    const int stride = gridDim.x * 256;
    for (int i = blockIdx.x * 256 + threadIdx.x; i < NN * 16; i += stride) {
        int n = i >> 4;
        int c0 = (i & 15) * 4;
        float4 v = *(const float4*)&vbase[(long)n * 64 + c0];
        float4 r = *(const float4*)&resbase[(long)n * 64 + c0];
        float4 o;
        o.x = fmaxf(fmaf(v.x, scale[c0 + 0], shift[c0 + 0]), 0.f) + r.x;
        o.y = fmaxf(fmaf(v.y, scale[c0 + 1], shift[c0 + 1]), 0.f) + r.y;
        o.z = fmaxf(fmaf(v.z, scale[c0 + 2], shift[c0 + 2]), 0.f) + r.z;
        o.w = fmaxf(fmaf(v.w, scale[c0 + 3], shift[c0 + 3]), 0.f) + r.w;
        *(float4*)&h[(long)n * 64 + c0] = o;
        if (hb) {
            union { ushort u[4]; uint2 v2; } p;
            p.u[0] = f2b(o.x); p.u[1] = f2b(o.y); p.u[2] = f2b(o.z); p.u[3] = f2b(o.w);
            *(uint2*)&hb[(long)n * 64 + c0] = p.v2;
        }
    }
}

// ---------------- edge MLP: wave-specialized producer/consumer pipeline ----------------
// 256 threads = 4 waves. Waves 0,1 = layer-1 producers (W1 half each);
// waves 2,3 = layer-2+3 consumers (W2 half each). 64-edge tiles, CONTIGUOUS
// chunk of tiles per block. Weights asm-pinned in VGPRs (no remat).
// Z1 crosses waves via double-buffered XOR-swizzled LDS; one barrier/tile.
#define EG 768
#define TPB 17     // ceil(12500 / 768)
#define ZROW 288   // z1 row stride in bytes (144 ushorts)

__global__ __launch_bounds__(256, 3) void edge_mlp_pipe_kernel(
    const ushort* __restrict__ hb,
    const int* __restrict__ src, const int* __restrict__ tgt,
    const ushort* __restrict__ W1b, const ushort* __restrict__ W2b,
    const float* __restrict__ b1, const float* __restrict__ b2,
    const float* __restrict__ W3, const float* __restrict__ b3,
    float* __restrict__ out)
{
    __shared__ ushort zbuf[2][64 * 144];
    __shared__ float red[2][2][64];

    const int tid = threadIdx.x;
    const int wid = tid >> 6, lane = tid & 63;
    const int l15 = lane & 15, l4 = lane >> 4;
    const bool isL1 = (wid < 2);
    const int os = wid & 1;
    const int ocb = os * 64;

    // persistent weights: this wave's layer only (64 VGPR), asm-pinned so the
    // allocator cannot rematerialize the loads inside the tile loop.
    const ushort* Wsrc = isL1 ? W1b : W2b;
    bf16x8 wf[4][4];
    float bn_[4], w3v[4];
    #pragma unroll
    for (int n = 0; n < 4; n++) {
        const int oc = ocb + n * 16 + l15;
        #pragma unroll
        for (int ks = 0; ks < 4; ks++)
            wf[n][ks] = *(const bf16x8*)&Wsrc[oc * 128 + ks * 32 + l4 * 8];
        bn_[n] = isL1 ? b1[oc] : b2[oc];
        w3v[n] = W3[oc];
    }
    float b3v = b3[0];
    #pragma unroll
    for (int n = 0; n < 4; n++) {
        #pragma unroll
        for (int ks = 0; ks < 4; ks++)
            asm volatile("" : "+v"(wf[n][ks]));
        asm volatile("" : "+v"(bn_[n]));
        asm volatile("" : "+v"(w3v[n]));
    }
    asm volatile("" : "+v"(b3v));

    const int bid = blockIdx.x;
    const int NT = NE / 64;                 // 12500 tiles
    const int t0 = bid * TPB;
    int nt = NT - t0;
    if (nt < 0) nt = 0;
    if (nt > TPB) nt = TPB;

    for (int j = 0; j < nt + 2; j++) {
        if (isL1) {
            if (j < nt) {
                const int e0 = (t0 + j) * 64;
                ushort* zb = zbuf[j & 1];
                #pragma unroll
                for (int h = 0; h < 2; h++) {          // ms halves -> small acc
                    f32x4 acc[2][4];
                    #pragma unroll
                    for (int m = 0; m < 2; m++)
                        #pragma unroll
                        for (int n = 0; n < 4; n++)
                            acc[m][n] = (f32x4){bn_[n], bn_[n], bn_[n], bn_[n]};
                    #pragma unroll
                    for (int m = 0; m < 2; m++) {
                        const int ms = h * 2 + m;
                        const int e = e0 + ms * 16 + l15;
                        const ushort* hs = hb + (long)src[e] * 64;
                        const ushort* ht = hb + (long)tgt[e] * 64;
                        #pragma unroll
                        for (int ks = 0; ks < 4; ks++) {
                            const ushort* bp = (ks < 2) ? hs : ht;
                            bf16x8 a = *(const bf16x8*)&bp[(ks & 1) * 32 + l4 * 8];
                            #pragma unroll
                            for (int n = 0; n < 4; n++)
                                acc[m][n] = __builtin_amdgcn_mfma_f32_16x16x32_bf16(a, wf[n][ks], acc[m][n], 0, 0, 0);
                        }
                    }
                    // write Z1 (relu, bf16) with XOR swizzle
                    #pragma unroll
                    for (int m = 0; m < 2; m++)
                        #pragma unroll
                        for (int n = 0; n < 4; n++) {
                            const int oc = ocb + n * 16 + l15;
                            #pragma unroll
                            for (int r = 0; r < 4; r++) {
                                const int row = (h * 2 + m) * 16 + l4 * 4 + r;
                                int byte = (row * ZROW + oc * 2) ^ (((row >> 2) & 3) << 4);
                                *(ushort*)((char*)zb + byte) = f2b(fmaxf(acc[m][n][r], 0.f));
                            }
                        }
                }
            }
            if (wid == 0 && j >= 2) {
                const int e0o = (t0 + (j - 2)) * 64;
                const int p = (j - 2) & 1;
                out[e0o + lane] = red[p][0][lane] + red[p][1][lane] + b3v;
            }
        } else {
            if (j >= 1 && j - 1 < nt) {
                const ushort* zb = zbuf[(j - 1) & 1];
                const int p = (j - 1) & 1;
                #pragma unroll
                for (int h = 0; h < 2; h++) {
                    f32x4 acc[2][4];
                    #pragma unroll
                    for (int m = 0; m < 2; m++)
                        #pragma unroll
                        for (int n = 0; n < 4; n++)
                            acc[m][n] = (f32x4){bn_[n], bn_[n], bn_[n], bn_[n]};
                    #pragma unroll
                    for (int m = 0; m < 2; m++) {
                        const int erow = (h * 2 + m) * 16 + l15;
                        #pragma unroll
                        for (int ks = 0; ks < 4; ks++) {
                            int byte = (erow * ZROW + ks * 64 + l4 * 16) ^ (((erow >> 2) & 3) << 4);
                            bf16x8 a = *(const bf16x8*)((const char*)zb + byte);
                            #pragma unroll
                            for (int n = 0; n < 4; n++)
                                acc[m][n] = __builtin_amdgcn_mfma_f32_16x16x32_bf16(a, wf[n][ks], acc[m][n], 0, 0, 0);
                        }
                    }
                    // layer 3 partial: relu(Z2)@W3 half, reduce over 16 oc-lanes
                    #pragma unroll
                    for (int m = 0; m < 2; m++)
                        #pragma unroll
                        for (int r = 0; r < 4; r++) {
                            float s = 0.f;
                            #pragma unroll
                            for (int n = 0; n < 4; n++)
                                s = fmaf(fmaxf(acc[m][n][r], 0.f), w3v[n], s);
                            s += __shfl_xor(s, 1);
                            s += __shfl_xor(s, 2);
                            s += __shfl_xor(s, 4);
                            s += __shfl_xor(s, 8);
                            if (l15 == 0)
                                red[p][os][(h * 2 + m) * 16 + l4 * 4 + r] = s;
                        }
                }
            }
        }
        __syncthreads();
    }
}

// ---------------- launch ----------------
extern "C" void kernel_launch(void* const* d_in, const int* in_sizes, int n_in,
                              void* d_out, int out_size, void* d_ws, size_t ws_size,
                              hipStream_t stream)
{
    const float* x   = (const float*)d_in[0];
    const int*   ei  = (const int*)d_in[1];
    const int* src = ei;
    const int* tgt = ei + NE;
    const float* Wl0 = (const float*)d_in[2];
    const float* bl0 = (const float*)d_in[3];
    const float* Wr0 = (const float*)d_in[4];
    const float* g0  = (const float*)d_in[5];
    const float* be0 = (const float*)d_in[6];
    const float* rW0 = (const float*)d_in[7];
    const float* rb0 = (const float*)d_in[8];
    const float* Wl1 = (const float*)d_in[9];
    const float* bl1 = (const float*)d_in[10];
    const float* Wr1 = (const float*)d_in[11];
    const float* g1  = (const float*)d_in[12];
    const float* be1 = (const float*)d_in[13];
    const float* Wl2 = (const float*)d_in[14];
    const float* bl2 = (const float*)d_in[15];
    const float* Wr2 = (const float*)d_in[16];
    const float* g2  = (const float*)d_in[17];
    const float* be2 = (const float*)d_in[18];
    const float* W1  = (const float*)d_in[19];
    const float* b1  = (const float*)d_in[20];
    const float* W2  = (const float*)d_in[21];
    const float* b2  = (const float*)d_in[22];
    const float* W3  = (const float*)d_in[23];
    const float* b3  = (const float*)d_in[24];
    float* out = (float*)d_out;

    float* ws = (float*)d_ws;
    float*  pre  = ws;                           // [0, 3.2M)
    float*  res  = ws + 3200000;                 // [3.2M, 6.4M)
    float*  hbuf = ws + 6400000;                 // [6.4M, 9.6M)
    float*  bn   = ws + 9600000;                 // 256
    float*  bnsum = bn, *bnsq = bn + 64, *bnsc = bn + 128, *bnsh = bn + 192;
    ushort* xb   = (ushort*)(ws + 9600256);      // floats [9600256, 11200256)
    ushort* hb   = (ushort*)(ws + 11200256);     // floats [11200256, 12800256)
    ushort* W1b  = (ushort*)(ws + 12800256);     // floats [12800256, 12808448)
    ushort* W2b  = W1b + 16384;                  // floats [12808448, 12816640)
    int*    icnt = (int*)(ws + 12816640);        // 50000
    int*    off  = icnt + 50000;                 // 50001
    int*    woff = off + 50001;                  // 50000
    int*    ebuf = woff + 50000;                 // 800000
    int*    bsum = ebuf + 800000;                // 256
    int*    bpre = bsum + 256;                   // 256

    // ---- one-time prep: bf16 weights + CSR ----
    prep_w_kernel<<<128, 256, 0, stream>>>(W1, W2, W1b, W2b);
    hipMemsetAsync(icnt, 0, NN * sizeof(int), stream);
    count_kernel<<<NE / 256, 256, 0, stream>>>(tgt, icnt);
    scan1_kernel<<<NBLK, 256, 0, stream>>>(icnt, off, bsum);
    scan2_kernel<<<1, 256, 0, stream>>>(bsum, bpre);
    scan3_kernel<<<NBLK, 256, 0, stream>>>(icnt, bpre, off, woff);
    fill_kernel<<<NE / 256, 256, 0, stream>>>(src, tgt, woff, ebuf);

    dim3 g0g(NBLK, 3), g12g(NBLK, 2);

    // ---- layer 0 ----
    hipMemsetAsync(bnsum, 0, 128 * sizeof(float), stream);
    proj_gemm_kernel<<<g0g, 256, 0, stream>>>(x, 128, Wl0, Wr0, rW0,
                                              bl0, rb0, xb, pre, res);
    gather_bn_kernel<<<1024, 256, 0, stream>>>(off, ebuf, xb, pre, bnsum, bnsq);
    bnfin_kernel<<<1, 64, 0, stream>>>(bnsum, bnsq, g0, be0, bnsc, bnsh);
    apply_kernel<<<1024, 256, 0, stream>>>(pre, res, bnsc, bnsh, hbuf, nullptr);

    // ---- layer 1 ----
    hipMemsetAsync(bnsum, 0, 128 * sizeof(float), stream);
    proj_gemm_kernel<<<g12g, 256, 0, stream>>>(hbuf, 64, Wl1, Wr1, nullptr,
                                               bl1, nullptr, xb, pre, res);
    gather_bn_kernel<<<1024, 256, 0, stream>>>(off, ebuf, xb, pre, bnsum, bnsq);
    bnfin_kernel<<<1, 64, 0, stream>>>(bnsum, bnsq, g1, be1, bnsc, bnsh);
    apply_kernel<<<1024, 256, 0, stream>>>(pre, hbuf, bnsc, bnsh, hbuf, nullptr);

    // ---- layer 2 ----
    hipMemsetAsync(bnsum, 0, 128 * sizeof(float), stream);
    proj_gemm_kernel<<<g12g, 256, 0, stream>>>(hbuf, 64, Wl2, Wr2, nullptr,
                                               bl2, nullptr, xb, pre, res);
    gather_bn_kernel<<<1024, 256, 0, stream>>>(off, ebuf, xb, pre, bnsum, bnsq);
    bnfin_kernel<<<1, 64, 0, stream>>>(bnsum, bnsq, g2, be2, bnsc, bnsh);
    apply_kernel<<<1024, 256, 0, stream>>>(pre, hbuf, bnsc, bnsh, hbuf, hb);

    // ---- edge MLP (wave-specialized pipeline, pinned weights) ----
    edge_mlp_pipe_kernel<<<EG, 256, 0, stream>>>(hb, src, tgt, W1b, W2b, b1, b2, W3, b3, out);
}

// Round 8
// 499.570 us; speedup vs baseline: 1.2621x; 1.2621x over previous
//
#include <hip/hip_runtime.h>
#include <hip/hip_bf16.h>

#define NN 50000
#define NE 800000
#define HID 64
#define EPSV 1e-5f
#define NBLK 196            // ceil(NN/256)

typedef __attribute__((ext_vector_type(8))) short bf16x8;
typedef __attribute__((ext_vector_type(4))) float f32x4;
typedef __attribute__((ext_vector_type(4))) int int4v;

__device__ __forceinline__ ushort f2b(float f) {
    union { __hip_bfloat16 b; ushort u; } c;
    c.b = __float2bfloat16(f);
    return c.u;
}
__device__ __forceinline__ float b2f(ushort u) {
    return __uint_as_float(((unsigned int)u) << 16);
}

// ---------------- weight f32 -> bf16 prep (edge MLP) ----------------
__global__ void prep_w_kernel(const float* __restrict__ W1, const float* __restrict__ W2,
                              ushort* __restrict__ W1b, ushort* __restrict__ W2b) {
    int i = blockIdx.x * 256 + threadIdx.x;   // 0..32767
    if (i < 16384) W1b[i] = f2b(W1[i]);
    else           W2b[i - 16384] = f2b(W2[i - 16384]);
}

// ---------------- CSR build: count, scan, fill ----------------
__global__ void count_kernel(const int* __restrict__ tgt, int* __restrict__ icnt) {
    int e = blockIdx.x * 256 + threadIdx.x;
    if (e < NE) atomicAdd(&icnt[tgt[e]], 1);
}

__global__ void scan1_kernel(const int* __restrict__ icnt, int* __restrict__ off,
                             int* __restrict__ bsum) {
    __shared__ int s[256];
    const int t = threadIdx.x;
    const int i = blockIdx.x * 256 + t;
    int v = (i < NN) ? icnt[i] : 0;
    s[t] = v;
    __syncthreads();
    for (int d = 1; d < 256; d <<= 1) {
        int x = (t >= d) ? s[t - d] : 0;
        __syncthreads();
        s[t] += x;
        __syncthreads();
    }
    if (i < NN) off[i] = s[t];             // inclusive, block-local
    if (t == 255) bsum[blockIdx.x] = s[255];
}

__global__ void scan2_kernel(const int* __restrict__ bsum, int* __restrict__ bpre) {
    __shared__ int s[256];
    const int t = threadIdx.x;
    int v = (t < NBLK) ? bsum[t] : 0;
    s[t] = v;
    __syncthreads();
    for (int d = 1; d < 256; d <<= 1) {
        int x = (t >= d) ? s[t - d] : 0;
        __syncthreads();
        s[t] += x;
        __syncthreads();
    }
    if (t < NBLK) bpre[t] = s[t] - v;      // exclusive
}

__global__ void scan3_kernel(const int* __restrict__ icnt, const int* __restrict__ bpre,
                             int* __restrict__ off, int* __restrict__ woff) {
    const int i = blockIdx.x * 256 + threadIdx.x;
    if (i < NN) {
        int e = off[i] - icnt[i] + bpre[blockIdx.x];   // exclusive global
        off[i] = e;
        woff[i] = e;
        if (i == NN - 1) off[NN] = NE;
    }
}

__global__ void fill_kernel(const int* __restrict__ src, const int* __restrict__ tgt,
                            int* __restrict__ woff, int* __restrict__ ebuf) {
    int e = blockIdx.x * 256 + threadIdx.x;
    if (e < NE) {
        int p = atomicAdd(&woff[tgt[e]], 1);
        ebuf[p] = src[e];
    }
}

// ---------------- projection GEMM ----------------
// seg0: xb (bf16) = A @ W0.T        seg1: pre = A @ W1s.T + bias1
// seg2: res = A @ W2s.T + bias2 (layer 0 only)
#define PADA 260
#define PADBW 68

__global__ __launch_bounds__(256, 2) void proj_gemm_kernel(
    const float* __restrict__ A, int K,
    const float* __restrict__ W0, const float* __restrict__ W1s,
    const float* __restrict__ W2s,
    const float* __restrict__ bias1, const float* __restrict__ bias2,
    ushort* __restrict__ xb, float* __restrict__ pre, float* __restrict__ res)
{
    __shared__ float At[32 * PADA];
    __shared__ float Bt[32 * PADBW];
    const int tid = threadIdx.x;
    const int seg = blockIdx.y;
    const float* W  = (seg == 0) ? W0 : ((seg == 1) ? W1s : W2s);
    const float* bp = (seg == 1) ? bias1 : ((seg == 2) ? bias2 : nullptr);
    const int n0 = blockIdx.x * 256;
    const int tn = tid & 31, to = tid >> 5;

    float bias[8];
    #pragma unroll
    for (int j = 0; j < 8; j++) bias[j] = bp ? bp[to * 8 + j] : 0.f;
    float acc[8][8];
    #pragma unroll
    for (int i = 0; i < 8; i++)
        #pragma unroll
        for (int j = 0; j < 8; j++) acc[i][j] = bias[j];

    for (int kc = 0; kc < K; kc += 32) {
        {
            const int nb = tid >> 3, k4 = (tid & 7) * 4;
            #pragma unroll
            for (int i = 0; i < 8; i++) {
                int col = nb + 32 * i;
                int n = n0 + col; if (n > NN - 1) n = NN - 1;
                float4 v = *(const float4*)&A[(long)n * K + kc + k4];
                int base = k4 * PADA + col;
                At[base] = v.x; At[base + PADA] = v.y;
                At[base + 2 * PADA] = v.z; At[base + 3 * PADA] = v.w;
            }
            const int oc = tid & 63, k8 = (tid >> 6) * 8;
            float4 w0 = *(const float4*)&W[(long)oc * K + kc + k8];
            float4 w1 = *(const float4*)&W[(long)oc * K + kc + k8 + 4];
            Bt[(k8 + 0) * PADBW + oc] = w0.x; Bt[(k8 + 1) * PADBW + oc] = w0.y;
            Bt[(k8 + 2) * PADBW + oc] = w0.z; Bt[(k8 + 3) * PADBW + oc] = w0.w;
            Bt[(k8 + 4) * PADBW + oc] = w1.x; Bt[(k8 + 5) * PADBW + oc] = w1.y;
            Bt[(k8 + 6) * PADBW + oc] = w1.z; Bt[(k8 + 7) * PADBW + oc] = w1.w;
        }
        __syncthreads();
        #pragma unroll 4
        for (int k = 0; k < 32; k++) {
            float4 a0 = *(const float4*)&At[k * PADA + tn * 4];
            float4 a1 = *(const float4*)&At[k * PADA + 128 + tn * 4];
            float4 b0 = *(const float4*)&Bt[k * PADBW + to * 8];
            float4 b1 = *(const float4*)&Bt[k * PADBW + to * 8 + 4];
            float av[8] = {a0.x, a0.y, a0.z, a0.w, a1.x, a1.y, a1.z, a1.w};
            float bv[8] = {b0.x, b0.y, b0.z, b0.w, b1.x, b1.y, b1.z, b1.w};
            #pragma unroll
            for (int i = 0; i < 8; i++)
                #pragma unroll
                for (int j = 0; j < 8; j++)
                    acc[i][j] = fmaf(av[i], bv[j], acc[i][j]);
        }
        __syncthreads();
    }
    #pragma unroll
    for (int i = 0; i < 8; i++) {
        int n = n0 + ((i < 4) ? (tn * 4 + i) : (128 + tn * 4 + i - 4));
        if (n < NN) {
            if (seg == 0) {
                union { ushort u[8]; int4v v; } pk;
                #pragma unroll
                for (int j = 0; j < 8; j++) pk.u[j] = f2b(acc[i][j]);
                *(int4v*)&xb[(long)n * 64 + to * 8] = pk.v;
            } else {
                float* O = (seg == 1) ? pre : res;
                float* cp = &O[(long)n * 64 + to * 8];
                *(float4*)cp       = make_float4(acc[i][0], acc[i][1], acc[i][2], acc[i][3]);
                *(float4*)(cp + 4) = make_float4(acc[i][4], acc[i][5], acc[i][6], acc[i][7]);
            }
        }
    }
}

// ---------------- gather (mean aggr, bf16 src) + self term + BN stats ----------------
__global__ __launch_bounds__(256) void gather_bn_kernel(
    const int* __restrict__ off, const int* __restrict__ ebuf,
    const ushort* __restrict__ xb,
    float* __restrict__ vbase,
    float* __restrict__ bnsum, float* __restrict__ bnsq)
{
    __shared__ float r1[4][64], r2[4][64];
    const int lane = threadIdx.x & 63;
    const int wid = __builtin_amdgcn_readfirstlane(threadIdx.x >> 6);
    float s = 0.f, q = 0.f;
    for (int n = blockIdx.x * 4 + wid; n < NN; n += gridDim.x * 4) {
        const int a = off[n], b = off[n + 1];
        float a0 = 0.f, a1 = 0.f, a2 = 0.f, a3 = 0.f;
        int p = a;
        for (; p + 4 <= b; p += 4) {
            int s0 = ebuf[p], s1 = ebuf[p + 1], s2 = ebuf[p + 2], s3 = ebuf[p + 3];
            a0 += b2f(xb[(long)s0 * 64 + lane]);
            a1 += b2f(xb[(long)s1 * 64 + lane]);
            a2 += b2f(xb[(long)s2 * 64 + lane]);
            a3 += b2f(xb[(long)s3 * 64 + lane]);
        }
        for (; p < b; ++p) a0 += b2f(xb[(long)ebuf[p] * 64 + lane]);
        float acc = (a0 + a1) + (a2 + a3);
        float v = acc / fmaxf((float)(b - a), 1.f) + vbase[(long)n * 64 + lane];
        vbase[(long)n * 64 + lane] = v;
        s += v; q += v * v;
    }
    r1[wid][lane] = s; r2[wid][lane] = q;
    __syncthreads();
    if (threadIdx.x < 64) {
        s = r1[0][lane] + r1[1][lane] + r1[2][lane] + r1[3][lane];
        q = r2[0][lane] + r2[1][lane] + r2[2][lane] + r2[3][lane];
        atomicAdd(&bnsum[lane], s);
        atomicAdd(&bnsq[lane], q);
    }
}

// ---------------- BN finalize ----------------
__global__ void bnfin_kernel(const float* __restrict__ bnsum, const float* __restrict__ bnsq,
                             const float* __restrict__ g, const float* __restrict__ be,
                             float* __restrict__ scale, float* __restrict__ shift)
{
    int c = threadIdx.x;  // 64
    float inv_n = 1.0f / (float)NN;
    float mu = bnsum[c] * inv_n;
    float var = bnsq[c] * inv_n - mu * mu;
    float rstd = rsqrtf(var + EPSV);
    float sc = g[c] * rstd;
    scale[c] = sc;
    shift[c] = be[c] - mu * sc;
}

// ---------------- BN apply + ReLU + residual ----------------
__global__ void apply_kernel(const float* __restrict__ vbase,
                             const float* __restrict__ resbase,
                             const float* __restrict__ scale, const float* __restrict__ shift,
                             float* __restrict__ h, ushort* hb)
{
    const int stride = gridDim.x * 256;
    for (int i = blockIdx.x * 256 + threadIdx.x; i < NN * 16; i += stride) {
        int n = i >> 4;
        int c0 = (i & 15) * 4;
        float4 v = *(const float4*)&vbase[(long)n * 64 + c0];
        float4 r = *(const float4*)&resbase[(long)n * 64 + c0];
        float4 o;
        o.x = fmaxf(fmaf(v.x, scale[c0 + 0], shift[c0 + 0]), 0.f) + r.x;
        o.y = fmaxf(fmaf(v.y, scale[c0 + 1], shift[c0 + 1]), 0.f) + r.y;
        o.z = fmaxf(fmaf(v.z, scale[c0 + 2], shift[c0 + 2]), 0.f) + r.z;
        o.w = fmaxf(fmaf(v.w, scale[c0 + 3], shift[c0 + 3]), 0.f) + r.w;
        *(float4*)&h[(long)n * 64 + c0] = o;
        if (hb) {
            union { ushort u[4]; uint2 v2; } p;
            p.u[0] = f2b(o.x); p.u[1] = f2b(o.y); p.u[2] = f2b(o.z); p.u[3] = f2b(o.w);
            *(uint2*)&hb[(long)n * 64 + c0] = p.v2;
        }
    }
}

// ---------------- edge MLP: LDS-weight MFMA, 512 threads, 128-edge tiles ----------------
// 8 waves = edges(4) x oc-half(2). Weights (both layers, bf16) staged once per
// block into XOR-swizzled LDS; B-frags ds_read per use (no register residency
// games). A-frags for L1 gathered directly from hb; next-tile gathers issued
// after the Z1 barrier so latency hides under L2-phase MFMAs. 2 barriers/tile.
#define NTILE 6250          // NE / 128
#define EMG 256

#define GATHER(tt)                                                        \
    do {                                                                  \
        int e0g = (t0 + (tt)) * 128;                                      \
        _Pragma("unroll")                                                 \
        for (int m = 0; m < 2; m++) {                                     \
            int e = e0g + we * 32 + m * 16 + l15;                         \
            const ushort* hs = hb + (long)src[e] * 64;                    \
            const ushort* ht = hb + (long)tgt[e] * 64;                    \
            ga[m][0] = *(const bf16x8*)&hs[l4 * 8];                       \
            ga[m][1] = *(const bf16x8*)&hs[32 + l4 * 8];                  \
            ga[m][2] = *(const bf16x8*)&ht[l4 * 8];                       \
            ga[m][3] = *(const bf16x8*)&ht[32 + l4 * 8];                  \
        }                                                                 \
    } while (0)

__global__ __launch_bounds__(512, 2) void edge_mlp_lds_kernel(
    const ushort* __restrict__ hb,
    const int* __restrict__ src, const int* __restrict__ tgt,
    const ushort* __restrict__ W1b, const ushort* __restrict__ W2b,
    const float* __restrict__ b1, const float* __restrict__ b2,
    const float* __restrict__ W3, const float* __restrict__ b3,
    float* __restrict__ out)
{
    __shared__ ushort wlds[32768];      // [layer][oc][k] bf16, 16B-chunk XOR swizzle
    __shared__ ushort z1[128 * 136];    // Z1 tile, row-major, padded
    __shared__ float red[2][2][128];    // double-buffered L3 partials

    const int tid = threadIdx.x;
    const int wid = tid >> 6, lane = tid & 63;
    const int l15 = lane & 15, l4 = lane >> 4;
    const int we = wid >> 1, wo = wid & 1;
    const int ocb = wo * 64;

    // ---- stage both weight layers into swizzled LDS ----
    for (int c = tid; c < 4096; c += 512) {
        int layer = c >> 11, oc = (c >> 4) & 127, kc = c & 15;
        const ushort* Wsrc = layer ? W2b : W1b;
        int4v v = *(const int4v*)&Wsrc[oc * 128 + kc * 8];
        int byte = layer * 32768 + oc * 256 + ((kc * 16) ^ ((oc & 7) << 4));
        *(int4v*)((char*)wlds + byte) = v;
    }

    float b1v[4], b2v[4], w3v[4];
    #pragma unroll
    for (int n = 0; n < 4; n++) {
        int oc = ocb + n * 16 + l15;
        b1v[n] = b1[oc]; b2v[n] = b2[oc]; w3v[n] = W3[oc];
    }
    const float b3v = b3[0];

    const int bid = blockIdx.x;
    const int q = NTILE / EMG, r = NTILE % EMG;      // 24, 106
    const int t0 = bid * q + (bid < r ? bid : r);
    const int nt = q + (bid < r ? 1 : 0);

    bf16x8 ga[2][4];
    GATHER(0);
    __syncthreads();                      // wlds ready

    for (int t = 0; t < nt; t++) {
        // ---- layer 1: acc = IN @ W1.T + b1, A-frags from registers ----
        f32x4 acc[2][4];
        #pragma unroll
        for (int m = 0; m < 2; m++)
            #pragma unroll
            for (int n = 0; n < 4; n++)
                acc[m][n] = (f32x4){b1v[n], b1v[n], b1v[n], b1v[n]};
        #pragma unroll
        for (int ks = 0; ks < 4; ks++) {
            bf16x8 wf[4];
            #pragma unroll
            for (int n = 0; n < 4; n++) {
                int oc = ocb + n * 16 + l15;
                int byte = oc * 256 + (((ks * 4 + l4) * 16) ^ ((oc & 7) << 4));
                wf[n] = *(const bf16x8*)((const char*)wlds + byte);
            }
            #pragma unroll
            for (int m = 0; m < 2; m++)
                #pragma unroll
                for (int n = 0; n < 4; n++)
                    acc[m][n] = __builtin_amdgcn_mfma_f32_16x16x32_bf16(ga[m][ks], wf[n], acc[m][n], 0, 0, 0);
        }
        // Z1 = relu(acc) -> LDS (bf16)
        #pragma unroll
        for (int m = 0; m < 2; m++)
            #pragma unroll
            for (int n = 0; n < 4; n++) {
                int col = ocb + n * 16 + l15;
                #pragma unroll
                for (int rr = 0; rr < 4; rr++) {
                    int row = we * 32 + m * 16 + l4 * 4 + rr;
                    z1[row * 136 + col] = f2b(fmaxf(acc[m][n][rr], 0.f));
                }
            }
        __syncthreads();                  // B1: Z1 ready

        // ---- prefetch next tile's A-gathers (hidden under L2 phase) ----
        if (t + 1 < nt) GATHER(t + 1);

        // ---- layer 2: acc2 = Z1 @ W2.T + b2 ----
        f32x4 acc2[2][4];
        #pragma unroll
        for (int m = 0; m < 2; m++)
            #pragma unroll
            for (int n = 0; n < 4; n++)
                acc2[m][n] = (f32x4){b2v[n], b2v[n], b2v[n], b2v[n]};
        #pragma unroll
        for (int ks = 0; ks < 4; ks++) {
            bf16x8 wf[4];
            #pragma unroll
            for (int n = 0; n < 4; n++) {
                int oc = ocb + n * 16 + l15;
                int byte = 32768 + oc * 256 + (((ks * 4 + l4) * 16) ^ ((oc & 7) << 4));
                wf[n] = *(const bf16x8*)((const char*)wlds + byte);
            }
            bf16x8 a2[2];
            #pragma unroll
            for (int m = 0; m < 2; m++)
                a2[m] = *(const bf16x8*)&z1[(we * 32 + m * 16 + l15) * 136 + ks * 32 + l4 * 8];
            #pragma unroll
            for (int m = 0; m < 2; m++)
                #pragma unroll
                for (int n = 0; n < 4; n++)
                    acc2[m][n] = __builtin_amdgcn_mfma_f32_16x16x32_bf16(a2[m], wf[n], acc2[m][n], 0, 0, 0);
        }

        // ---- layer 3: partials over oc-half, 16-lane shfl reduce ----
        #pragma unroll
        for (int m = 0; m < 2; m++)
            #pragma unroll
            for (int rr = 0; rr < 4; rr++) {
                float s = 0.f;
                #pragma unroll
                for (int n = 0; n < 4; n++)
                    s = fmaf(fmaxf(acc2[m][n][rr], 0.f), w3v[n], s);
                s += __shfl_xor(s, 1);
                s += __shfl_xor(s, 2);
                s += __shfl_xor(s, 4);
                s += __shfl_xor(s, 8);
                if (l15 == 0)
                    red[t & 1][wo][we * 32 + m * 16 + l4 * 4 + rr] = s;
            }
        __syncthreads();                  // B2: red ready, Z1 consumed
        if (tid < 128)
            out[(t0 + t) * 128 + tid] = red[t & 1][0][tid] + red[t & 1][1][tid] + b3v;
    }
}

// ---------------- launch ----------------
extern "C" void kernel_launch(void* const* d_in, const int* in_sizes, int n_in,
                              void* d_out, int out_size, void* d_ws, size_t ws_size,
                              hipStream_t stream)
{
    const float* x   = (const float*)d_in[0];
    const int*   ei  = (const int*)d_in[1];
    const int* src = ei;
    const int* tgt = ei + NE;
    const float* Wl0 = (const float*)d_in[2];
    const float* bl0 = (const float*)d_in[3];
    const float* Wr0 = (const float*)d_in[4];
    const float* g0  = (const float*)d_in[5];
    const float* be0 = (const float*)d_in[6];
    const float* rW0 = (const float*)d_in[7];
    const float* rb0 = (const float*)d_in[8];
    const float* Wl1 = (const float*)d_in[9];
    const float* bl1 = (const float*)d_in[10];
    const float* Wr1 = (const float*)d_in[11];
    const float* g1  = (const float*)d_in[12];
    const float* be1 = (const float*)d_in[13];
    const float* Wl2 = (const float*)d_in[14];
    const float* bl2 = (const float*)d_in[15];
    const float* Wr2 = (const float*)d_in[16];
    const float* g2  = (const float*)d_in[17];
    const float* be2 = (const float*)d_in[18];
    const float* W1  = (const float*)d_in[19];
    const float* b1  = (const float*)d_in[20];
    const float* W2  = (const float*)d_in[21];
    const float* b2  = (const float*)d_in[22];
    const float* W3  = (const float*)d_in[23];
    const float* b3  = (const float*)d_in[24];
    float* out = (float*)d_out;

    float* ws = (float*)d_ws;
    float*  pre  = ws;                           // [0, 3.2M)
    float*  res  = ws + 3200000;                 // [3.2M, 6.4M)
    float*  hbuf = ws + 6400000;                 // [6.4M, 9.6M)
    float*  bn   = ws + 9600000;                 // 256
    float*  bnsum = bn, *bnsq = bn + 64, *bnsc = bn + 128, *bnsh = bn + 192;
    ushort* xb   = (ushort*)(ws + 9600256);      // floats [9600256, 11200256)
    ushort* hb   = (ushort*)(ws + 11200256);     // floats [11200256, 12800256)
    ushort* W1b  = (ushort*)(ws + 12800256);     // floats [12800256, 12808448)
    ushort* W2b  = W1b + 16384;                  // floats [12808448, 12816640)
    int*    icnt = (int*)(ws + 12816640);        // 50000
    int*    off  = icnt + 50000;                 // 50001
    int*    woff = off + 50001;                  // 50000
    int*    ebuf = woff + 50000;                 // 800000
    int*    bsum = ebuf + 800000;                // 256
    int*    bpre = bsum + 256;                   // 256

    // ---- one-time prep: bf16 weights + CSR ----
    prep_w_kernel<<<128, 256, 0, stream>>>(W1, W2, W1b, W2b);
    hipMemsetAsync(icnt, 0, NN * sizeof(int), stream);
    count_kernel<<<NE / 256, 256, 0, stream>>>(tgt, icnt);
    scan1_kernel<<<NBLK, 256, 0, stream>>>(icnt, off, bsum);
    scan2_kernel<<<1, 256, 0, stream>>>(bsum, bpre);
    scan3_kernel<<<NBLK, 256, 0, stream>>>(icnt, bpre, off, woff);
    fill_kernel<<<NE / 256, 256, 0, stream>>>(src, tgt, woff, ebuf);

    dim3 g0g(NBLK, 3), g12g(NBLK, 2);

    // ---- layer 0 ----
    hipMemsetAsync(bnsum, 0, 128 * sizeof(float), stream);
    proj_gemm_kernel<<<g0g, 256, 0, stream>>>(x, 128, Wl0, Wr0, rW0,
                                              bl0, rb0, xb, pre, res);
    gather_bn_kernel<<<1024, 256, 0, stream>>>(off, ebuf, xb, pre, bnsum, bnsq);
    bnfin_kernel<<<1, 64, 0, stream>>>(bnsum, bnsq, g0, be0, bnsc, bnsh);
    apply_kernel<<<1024, 256, 0, stream>>>(pre, res, bnsc, bnsh, hbuf, nullptr);

    // ---- layer 1 ----
    hipMemsetAsync(bnsum, 0, 128 * sizeof(float), stream);
    proj_gemm_kernel<<<g12g, 256, 0, stream>>>(hbuf, 64, Wl1, Wr1, nullptr,
                                               bl1, nullptr, xb, pre, res);
    gather_bn_kernel<<<1024, 256, 0, stream>>>(off, ebuf, xb, pre, bnsum, bnsq);
    bnfin_kernel<<<1, 64, 0, stream>>>(bnsum, bnsq, g1, be1, bnsc, bnsh);
    apply_kernel<<<1024, 256, 0, stream>>>(pre, hbuf, bnsc, bnsh, hbuf, nullptr);

    // ---- layer 2 ----
    hipMemsetAsync(bnsum, 0, 128 * sizeof(float), stream);
    proj_gemm_kernel<<<g12g, 256, 0, stream>>>(hbuf, 64, Wl2, Wr2, nullptr,
                                               bl2, nullptr, xb, pre, res);
    gather_bn_kernel<<<1024, 256, 0, stream>>>(off, ebuf, xb, pre, bnsum, bnsq);
    bnfin_kernel<<<1, 64, 0, stream>>>(bnsum, bnsq, g2, be2, bnsc, bnsh);
    apply_kernel<<<1024, 256, 0, stream>>>(pre, hbuf, bnsc, bnsh, hbuf, hb);

    // ---- edge MLP (LDS-weight MFMA) ----
    edge_mlp_lds_kernel<<<EMG, 512, 0, stream>>>(hb, src, tgt, W1b, W2b, b1, b2, W3, b3, out);
}

// Round 9
// 482.096 us; speedup vs baseline: 1.3078x; 1.0362x over previous
//
#include <hip/hip_runtime.h>
#include <hip/hip_bf16.h>

#define NN 50000
#define NE 800000
#define HID 64
#define EPSV 1e-5f
#define NBLK 196            // ceil(NN/256)

typedef __attribute__((ext_vector_type(8))) short bf16x8;
typedef __attribute__((ext_vector_type(4))) float f32x4;
typedef __attribute__((ext_vector_type(4))) int int4v;

__device__ __forceinline__ ushort f2b(float f) {
    union { __hip_bfloat16 b; ushort u; } c;
    c.b = __float2bfloat16(f);
    return c.u;
}
__device__ __forceinline__ float b2f(ushort u) {
    return __uint_as_float(((unsigned int)u) << 16);
}

// ---------------- edge-MLP weight f32 -> bf16 ----------------
__global__ void prep_w_kernel(const float* __restrict__ W1, const float* __restrict__ W2,
                              ushort* __restrict__ W1b, ushort* __restrict__ W2b) {
    int i = blockIdx.x * 256 + threadIdx.x;   // 0..32767
    if (i < 16384) W1b[i] = f2b(W1[i]);
    else           W2b[i - 16384] = f2b(W2[i - 16384]);
}

// ---------------- node-path weights f32 -> bf16 (packed buffer) ----------------
// layout: Wl0[8192] Wr0[8192] rW0[8192] Wl1[4096] Wr1[4096] Wl2[4096] Wr2[4096]
__global__ void prep_nodew_kernel(
    const float* __restrict__ Wl0, const float* __restrict__ Wr0, const float* __restrict__ rW0,
    const float* __restrict__ Wl1, const float* __restrict__ Wr1,
    const float* __restrict__ Wl2, const float* __restrict__ Wr2,
    ushort* __restrict__ wnb)
{
    int i = blockIdx.x * 256 + threadIdx.x;   // 0..40959
    if      (i < 8192)  wnb[i] = f2b(Wl0[i]);
    else if (i < 16384) wnb[i] = f2b(Wr0[i - 8192]);
    else if (i < 24576) wnb[i] = f2b(rW0[i - 16384]);
    else if (i < 28672) wnb[i] = f2b(Wl1[i - 24576]);
    else if (i < 32768) wnb[i] = f2b(Wr1[i - 28672]);
    else if (i < 36864) wnb[i] = f2b(Wl2[i - 32768]);
    else if (i < 40960) wnb[i] = f2b(Wr2[i - 36864]);
}

// ---------------- x f32 -> bf16 ----------------
__global__ void xcvt_kernel(const float* __restrict__ x, ushort* __restrict__ xq) {
    int i = blockIdx.x * 256 + threadIdx.x;   // 0..799999, 8 elems each
    float4 a = *(const float4*)&x[i * 8];
    float4 b = *(const float4*)&x[i * 8 + 4];
    union { ushort u[8]; int4v v; } pk;
    pk.u[0] = f2b(a.x); pk.u[1] = f2b(a.y); pk.u[2] = f2b(a.z); pk.u[3] = f2b(a.w);
    pk.u[4] = f2b(b.x); pk.u[5] = f2b(b.y); pk.u[6] = f2b(b.z); pk.u[7] = f2b(b.w);
    *(int4v*)&xq[i * 8] = pk.v;
}

// ---------------- CSR build: count, scan, fill ----------------
__global__ void count_kernel(const int* __restrict__ tgt, int* __restrict__ icnt) {
    int e = blockIdx.x * 256 + threadIdx.x;
    if (e < NE) atomicAdd(&icnt[tgt[e]], 1);
}

__global__ void scan1_kernel(const int* __restrict__ icnt, int* __restrict__ off,
                             int* __restrict__ bsum) {
    __shared__ int s[256];
    const int t = threadIdx.x;
    const int i = blockIdx.x * 256 + t;
    int v = (i < NN) ? icnt[i] : 0;
    s[t] = v;
    __syncthreads();
    for (int d = 1; d < 256; d <<= 1) {
        int x = (t >= d) ? s[t - d] : 0;
        __syncthreads();
        s[t] += x;
        __syncthreads();
    }
    if (i < NN) off[i] = s[t];             // inclusive, block-local
    if (t == 255) bsum[blockIdx.x] = s[255];
}

__global__ void scan2_kernel(const int* __restrict__ bsum, int* __restrict__ bpre) {
    __shared__ int s[256];
    const int t = threadIdx.x;
    int v = (t < NBLK) ? bsum[t] : 0;
    s[t] = v;
    __syncthreads();
    for (int d = 1; d < 256; d <<= 1) {
        int x = (t >= d) ? s[t - d] : 0;
        __syncthreads();
        s[t] += x;
        __syncthreads();
    }
    if (t < NBLK) bpre[t] = s[t] - v;      // exclusive
}

__global__ void scan3_kernel(const int* __restrict__ icnt, const int* __restrict__ bpre,
                             int* __restrict__ off, int* __restrict__ woff) {
    const int i = blockIdx.x * 256 + threadIdx.x;
    if (i < NN) {
        int e = off[i] - icnt[i] + bpre[blockIdx.x];   // exclusive global
        off[i] = e;
        woff[i] = e;
        if (i == NN - 1) off[NN] = NE;
    }
}

__global__ void fill_kernel(const int* __restrict__ src, const int* __restrict__ tgt,
                            int* __restrict__ woff, int* __restrict__ ebuf) {
    int e = blockIdx.x * 256 + threadIdx.x;
    if (e < NE) {
        int p = atomicAdd(&woff[tgt[e]], 1);
        ebuf[p] = src[e];
    }
}

// ---------------- projection GEMM via MFMA (bf16 in, f32 acc) ----------------
// One 128-node x 64-oc tile per block (no tile loop -> weights used once, no
// remat/spill hazard). seg0 -> xb (bf16), seg1 -> pre + bias1, seg2 -> res + bias2.
template<int K>
__global__ __launch_bounds__(256) void proj_mfma_kernel(
    const ushort* __restrict__ Ab,
    const ushort* __restrict__ w0, const ushort* __restrict__ w1,
    const ushort* __restrict__ w2,
    const float* __restrict__ bias1, const float* __restrict__ bias2,
    ushort* __restrict__ xb, float* __restrict__ pre, float* __restrict__ res)
{
    __shared__ float sC[128][65];
    const int tid = threadIdx.x;
    const int wv = tid >> 6, lane = tid & 63;
    const int l15 = lane & 15, l4 = lane >> 4;
    const int seg = blockIdx.y;
    const ushort* W = (seg == 0) ? w0 : ((seg == 1) ? w1 : w2);
    const int n0 = blockIdx.x * 128;
    constexpr int KS = K / 32;

    bf16x8 wf[4][KS];
    #pragma unroll
    for (int n = 0; n < 4; n++)
        #pragma unroll
        for (int ks = 0; ks < KS; ks++)
            wf[n][ks] = *(const bf16x8*)&W[(n * 16 + l15) * K + ks * 32 + l4 * 8];

    f32x4 acc[2][4];
    #pragma unroll
    for (int m = 0; m < 2; m++)
        #pragma unroll
        for (int n = 0; n < 4; n++)
            acc[m][n] = (f32x4){0.f, 0.f, 0.f, 0.f};

    #pragma unroll
    for (int m = 0; m < 2; m++) {
        int row = n0 + wv * 32 + m * 16 + l15;
        if (row > NN - 1) row = NN - 1;
        #pragma unroll
        for (int ks = 0; ks < KS; ks++) {
            bf16x8 a = *(const bf16x8*)&Ab[(long)row * K + ks * 32 + l4 * 8];
            #pragma unroll
            for (int n = 0; n < 4; n++)
                acc[m][n] = __builtin_amdgcn_mfma_f32_16x16x32_bf16(a, wf[n][ks], acc[m][n], 0, 0, 0);
        }
    }
    #pragma unroll
    for (int m = 0; m < 2; m++)
        #pragma unroll
        for (int n = 0; n < 4; n++)
            #pragma unroll
            for (int r = 0; r < 4; r++)
                sC[wv * 32 + m * 16 + l4 * 4 + r][n * 16 + l15] = acc[m][n][r];
    __syncthreads();

    const int r = tid >> 1, ch = (tid & 1) * 32;
    const int node = n0 + r;
    if (node < NN) {
        if (seg == 0) {
            #pragma unroll
            for (int g = 0; g < 4; g++) {
                union { ushort u[8]; int4v v; } pk;
                #pragma unroll
                for (int j = 0; j < 8; j++)
                    pk.u[j] = f2b(sC[r][ch + g * 8 + j]);
                *(int4v*)&xb[(long)node * 64 + ch + g * 8] = pk.v;
            }
        } else {
            float* O = (seg == 1) ? pre : res;
            const float* bp = (seg == 1) ? bias1 : bias2;
            #pragma unroll
            for (int g = 0; g < 8; g++) {
                int c = ch + g * 4;
                float4 v = make_float4(sC[r][c + 0] + bp[c + 0], sC[r][c + 1] + bp[c + 1],
                                       sC[r][c + 2] + bp[c + 2], sC[r][c + 3] + bp[c + 3]);
                *(float4*)&O[(long)node * 64 + c] = v;
            }
        }
    }
}

// ---------------- gather (mean aggr, bf16 src) + self term + BN stats ----------------
__global__ __launch_bounds__(256) void gather_bn_kernel(
    const int* __restrict__ off, const int* __restrict__ ebuf,
    const ushort* __restrict__ xb,
    float* __restrict__ vbase,
    float* __restrict__ bnsum, float* __restrict__ bnsq)
{
    __shared__ float r1[4][64], r2[4][64];
    const int lane = threadIdx.x & 63;
    const int wid = __builtin_amdgcn_readfirstlane(threadIdx.x >> 6);
    float s = 0.f, q = 0.f;
    for (int n = blockIdx.x * 4 + wid; n < NN; n += gridDim.x * 4) {
        const int a = off[n], b = off[n + 1];
        float a0 = 0.f, a1 = 0.f, a2 = 0.f, a3 = 0.f;
        int p = a;
        for (; p + 4 <= b; p += 4) {
            int s0 = ebuf[p], s1 = ebuf[p + 1], s2 = ebuf[p + 2], s3 = ebuf[p + 3];
            a0 += b2f(xb[(long)s0 * 64 + lane]);
            a1 += b2f(xb[(long)s1 * 64 + lane]);
            a2 += b2f(xb[(long)s2 * 64 + lane]);
            a3 += b2f(xb[(long)s3 * 64 + lane]);
        }
        for (; p < b; ++p) a0 += b2f(xb[(long)ebuf[p] * 64 + lane]);
        float acc = (a0 + a1) + (a2 + a3);
        float v = acc / fmaxf((float)(b - a), 1.f) + vbase[(long)n * 64 + lane];
        vbase[(long)n * 64 + lane] = v;
        s += v; q += v * v;
    }
    r1[wid][lane] = s; r2[wid][lane] = q;
    __syncthreads();
    if (threadIdx.x < 64) {
        s = r1[0][lane] + r1[1][lane] + r1[2][lane] + r1[3][lane];
        q = r2[0][lane] + r2[1][lane] + r2[2][lane] + r2[3][lane];
        atomicAdd(&bnsum[lane], s);
        atomicAdd(&bnsq[lane], q);
    }
}

// ---------------- BN finalize + apply + ReLU + residual (fused) ----------------
__global__ void apply_bn_kernel(const float* __restrict__ vbase,
                                const float* __restrict__ resbase,
                                const float* __restrict__ bnsum, const float* __restrict__ bnsq,
                                const float* __restrict__ g, const float* __restrict__ be,
                                float* __restrict__ h, ushort* __restrict__ hb)
{
    const float inv_n = 1.0f / (float)NN;
    const int stride = gridDim.x * 256;
    for (int i = blockIdx.x * 256 + threadIdx.x; i < NN * 16; i += stride) {
        int n = i >> 4;
        int c0 = (i & 15) * 4;
        float sc[4], sh[4];
        #pragma unroll
        for (int j = 0; j < 4; j++) {
            int c = c0 + j;
            float mu = bnsum[c] * inv_n;
            float var = bnsq[c] * inv_n - mu * mu;
            float rstd = rsqrtf(var + EPSV);
            sc[j] = g[c] * rstd;
            sh[j] = be[c] - mu * sc[j];
        }
        float4 v = *(const float4*)&vbase[(long)n * 64 + c0];
        float4 r = *(const float4*)&resbase[(long)n * 64 + c0];
        float4 o;
        o.x = fmaxf(fmaf(v.x, sc[0], sh[0]), 0.f) + r.x;
        o.y = fmaxf(fmaf(v.y, sc[1], sh[1]), 0.f) + r.y;
        o.z = fmaxf(fmaf(v.z, sc[2], sh[2]), 0.f) + r.z;
        o.w = fmaxf(fmaf(v.w, sc[3], sh[3]), 0.f) + r.w;
        *(float4*)&h[(long)n * 64 + c0] = o;
        union { ushort u[4]; uint2 v2; } p;
        p.u[0] = f2b(o.x); p.u[1] = f2b(o.y); p.u[2] = f2b(o.z); p.u[3] = f2b(o.w);
        *(uint2*)&hb[(long)n * 64 + c0] = p.v2;
    }
}

// ---------------- edge MLP: LDS-weight MFMA, 512 threads, 128-edge tiles ----------------
// z1 accesses XOR-swizzled by row to break the 8-way ds_read_b128 conflict.
#define NTILE 6250          // NE / 128
#define EMG 256
#define Z1B(row, usc) ((((row) * 272) + ((usc) * 2)) ^ ((((row) >> 1) & 7) << 4))

#define GATHER(tt)                                                        \
    do {                                                                  \
        int e0g = (t0 + (tt)) * 128;                                      \
        _Pragma("unroll")                                                 \
        for (int m = 0; m < 2; m++) {                                     \
            int e = e0g + we * 32 + m * 16 + l15;                         \
            const ushort* hs = hb + (long)src[e] * 64;                    \
            const ushort* ht = hb + (long)tgt[e] * 64;                    \
            ga[m][0] = *(const bf16x8*)&hs[l4 * 8];                       \
            ga[m][1] = *(const bf16x8*)&hs[32 + l4 * 8];                  \
            ga[m][2] = *(const bf16x8*)&ht[l4 * 8];                       \
            ga[m][3] = *(const bf16x8*)&ht[32 + l4 * 8];                  \
        }                                                                 \
    } while (0)

__global__ __launch_bounds__(512, 2) void edge_mlp_lds_kernel(
    const ushort* __restrict__ hb,
    const int* __restrict__ src, const int* __restrict__ tgt,
    const ushort* __restrict__ W1b, const ushort* __restrict__ W2b,
    const float* __restrict__ b1, const float* __restrict__ b2,
    const float* __restrict__ W3, const float* __restrict__ b3,
    float* __restrict__ out)
{
    __shared__ ushort wlds[32768];      // [layer][oc][k] bf16, 16B-chunk XOR swizzle
    __shared__ ushort z1[128 * 136];    // Z1 tile, row-swizzled
    __shared__ float red[2][2][128];    // double-buffered L3 partials

    const int tid = threadIdx.x;
    const int wid = tid >> 6, lane = tid & 63;
    const int l15 = lane & 15, l4 = lane >> 4;
    const int we = wid >> 1, wo = wid & 1;
    const int ocb = wo * 64;

    // ---- stage both weight layers into swizzled LDS ----
    for (int c = tid; c < 4096; c += 512) {
        int layer = c >> 11, oc = (c >> 4) & 127, kc = c & 15;
        const ushort* Wsrc = layer ? W2b : W1b;
        int4v v = *(const int4v*)&Wsrc[oc * 128 + kc * 8];
        int byte = layer * 32768 + oc * 256 + ((kc * 16) ^ ((oc & 7) << 4));
        *(int4v*)((char*)wlds + byte) = v;
    }

    float b1v[4], b2v[4], w3v[4];
    #pragma unroll
    for (int n = 0; n < 4; n++) {
        int oc = ocb + n * 16 + l15;
        b1v[n] = b1[oc]; b2v[n] = b2[oc]; w3v[n] = W3[oc];
    }
    const float b3v = b3[0];

    const int bid = blockIdx.x;
    const int q = NTILE / EMG, r = NTILE % EMG;      // 24, 106
    const int t0 = bid * q + (bid < r ? bid : r);
    const int nt = q + (bid < r ? 1 : 0);

    bf16x8 ga[2][4];
    GATHER(0);
    __syncthreads();                      // wlds ready

    for (int t = 0; t < nt; t++) {
        // ---- layer 1: acc = IN @ W1.T + b1, A-frags from registers ----
        f32x4 acc[2][4];
        #pragma unroll
        for (int m = 0; m < 2; m++)
            #pragma unroll
            for (int n = 0; n < 4; n++)
                acc[m][n] = (f32x4){b1v[n], b1v[n], b1v[n], b1v[n]};
        #pragma unroll
        for (int ks = 0; ks < 4; ks++) {
            bf16x8 wf[4];
            #pragma unroll
            for (int n = 0; n < 4; n++) {
                int oc = ocb + n * 16 + l15;
                int byte = oc * 256 + (((ks * 4 + l4) * 16) ^ ((oc & 7) << 4));
                wf[n] = *(const bf16x8*)((const char*)wlds + byte);
            }
            #pragma unroll
            for (int m = 0; m < 2; m++)
                #pragma unroll
                for (int n = 0; n < 4; n++)
                    acc[m][n] = __builtin_amdgcn_mfma_f32_16x16x32_bf16(ga[m][ks], wf[n], acc[m][n], 0, 0, 0);
        }
        // Z1 = relu(acc) -> LDS (bf16), row-swizzled
        #pragma unroll
        for (int m = 0; m < 2; m++)
            #pragma unroll
            for (int n = 0; n < 4; n++) {
                int col = ocb + n * 16 + l15;
                #pragma unroll
                for (int rr = 0; rr < 4; rr++) {
                    int row = we * 32 + m * 16 + l4 * 4 + rr;
                    *(ushort*)((char*)z1 + Z1B(row, col)) = f2b(fmaxf(acc[m][n][rr], 0.f));
                }
            }
        __syncthreads();                  // B1: Z1 ready

        // ---- prefetch next tile's A-gathers (hidden under L2 phase) ----
        if (t + 1 < nt) GATHER(t + 1);

        // ---- layer 2: acc2 = Z1 @ W2.T + b2 ----
        f32x4 acc2[2][4];
        #pragma unroll
        for (int m = 0; m < 2; m++)
            #pragma unroll
            for (int n = 0; n < 4; n++)
                acc2[m][n] = (f32x4){b2v[n], b2v[n], b2v[n], b2v[n]};
        #pragma unroll
        for (int ks = 0; ks < 4; ks++) {
            bf16x8 wf[4];
            #pragma unroll
            for (int n = 0; n < 4; n++) {
                int oc = ocb + n * 16 + l15;
                int byte = 32768 + oc * 256 + (((ks * 4 + l4) * 16) ^ ((oc & 7) << 4));
                wf[n] = *(const bf16x8*)((const char*)wlds + byte);
            }
            bf16x8 a2[2];
            #pragma unroll
            for (int m = 0; m < 2; m++) {
                int erow = we * 32 + m * 16 + l15;
                a2[m] = *(const bf16x8*)((const char*)z1 + Z1B(erow, ks * 32 + l4 * 8));
            }
            #pragma unroll
            for (int m = 0; m < 2; m++)
                #pragma unroll
                for (int n = 0; n < 4; n++)
                    acc2[m][n] = __builtin_amdgcn_mfma_f32_16x16x32_bf16(a2[m], wf[n], acc2[m][n], 0, 0, 0);
        }

        // ---- layer 3: partials over oc-half, 16-lane shfl reduce ----
        #pragma unroll
        for (int m = 0; m < 2; m++)
            #pragma unroll
            for (int rr = 0; rr < 4; rr++) {
                float s = 0.f;
                #pragma unroll
                for (int n = 0; n < 4; n++)
                    s = fmaf(fmaxf(acc2[m][n][rr], 0.f), w3v[n], s);
                s += __shfl_xor(s, 1);
                s += __shfl_xor(s, 2);
                s += __shfl_xor(s, 4);
                s += __shfl_xor(s, 8);
                if (l15 == 0)
                    red[t & 1][wo][we * 32 + m * 16 + l4 * 4 + rr] = s;
            }
        __syncthreads();                  // B2: red ready, Z1 consumed
        if (tid < 128)
            out[(t0 + t) * 128 + tid] = red[t & 1][0][tid] + red[t & 1][1][tid] + b3v;
    }
}

// ---------------- launch ----------------
extern "C" void kernel_launch(void* const* d_in, const int* in_sizes, int n_in,
                              void* d_out, int out_size, void* d_ws, size_t ws_size,
                              hipStream_t stream)
{
    const float* x   = (const float*)d_in[0];
    const int*   ei  = (const int*)d_in[1];
    const int* src = ei;
    const int* tgt = ei + NE;
    const float* Wl0 = (const float*)d_in[2];
    const float* bl0 = (const float*)d_in[3];
    const float* Wr0 = (const float*)d_in[4];
    const float* g0  = (const float*)d_in[5];
    const float* be0 = (const float*)d_in[6];
    const float* rW0 = (const float*)d_in[7];
    const float* rb0 = (const float*)d_in[8];
    const float* Wl1 = (const float*)d_in[9];
    const float* bl1 = (const float*)d_in[10];
    const float* Wr1 = (const float*)d_in[11];
    const float* g1  = (const float*)d_in[12];
    const float* be1 = (const float*)d_in[13];
    const float* Wl2 = (const float*)d_in[14];
    const float* bl2 = (const float*)d_in[15];
    const float* Wr2 = (const float*)d_in[16];
    const float* g2  = (const float*)d_in[17];
    const float* be2 = (const float*)d_in[18];
    const float* W1  = (const float*)d_in[19];
    const float* b1  = (const float*)d_in[20];
    const float* W2  = (const float*)d_in[21];
    const float* b2  = (const float*)d_in[22];
    const float* W3  = (const float*)d_in[23];
    const float* b3  = (const float*)d_in[24];
    float* out = (float*)d_out;

    float* ws = (float*)d_ws;
    float*  pre  = ws;                           // [0, 3.2M)
    float*  res  = ws + 3200000;                 // [3.2M, 6.4M)
    float*  hbuf = ws + 6400000;                 // [6.4M, 9.6M)
    float*  bn   = ws + 9600000;                 // 256
    float*  bnsum = bn, *bnsq = bn + 64;
    ushort* xb   = (ushort*)(ws + 9600256);      // floats [9600256, 11200256)
    ushort* hb   = (ushort*)(ws + 11200256);     // floats [11200256, 12800256)
    ushort* W1b  = (ushort*)(ws + 12800256);     // floats [12800256, 12808448)
    ushort* W2b  = W1b + 16384;                  // floats [12808448, 12816640)
    int*    icnt = (int*)(ws + 12816640);        // 50000
    int*    off  = icnt + 50000;                 // 50001
    int*    woff = off + 50001;                  // 50000
    int*    ebuf = woff + 50000;                 // 800000
    int*    bsum = ebuf + 800000;                // 256
    int*    bpre = bsum + 256;                   // 256 -> ends at float 13767153
    ushort* wnb  = (ushort*)(ws + 13767153);     // 40960 ushorts
    ushort* Wl0b = wnb;
    ushort* Wr0b = wnb + 8192;
    ushort* rW0b = wnb + 16384;
    ushort* Wl1b = wnb + 24576;
    ushort* Wr1b = wnb + 28672;
    ushort* Wl2b = wnb + 32768;
    ushort* Wr2b = wnb + 36864;
    ushort* xb16 = (ushort*)hbuf;                // x in bf16; dead once apply_bn L0 writes hbuf

    // ---- one-time prep: bf16 weights + x + CSR ----
    prep_w_kernel<<<128, 256, 0, stream>>>(W1, W2, W1b, W2b);
    prep_nodew_kernel<<<160, 256, 0, stream>>>(Wl0, Wr0, rW0, Wl1, Wr1, Wl2, Wr2, wnb);
    xcvt_kernel<<<3125, 256, 0, stream>>>(x, xb16);
    hipMemsetAsync(icnt, 0, NN * sizeof(int), stream);
    count_kernel<<<NE / 256, 256, 0, stream>>>(tgt, icnt);
    scan1_kernel<<<NBLK, 256, 0, stream>>>(icnt, off, bsum);
    scan2_kernel<<<1, 256, 0, stream>>>(bsum, bpre);
    scan3_kernel<<<NBLK, 256, 0, stream>>>(icnt, bpre, off, woff);
    fill_kernel<<<NE / 256, 256, 0, stream>>>(src, tgt, woff, ebuf);

    dim3 g0g(391, 3), g12g(391, 2);

    // ---- layer 0 ----
    hipMemsetAsync(bnsum, 0, 128 * sizeof(float), stream);
    proj_mfma_kernel<128><<<g0g, 256, 0, stream>>>(xb16, Wl0b, Wr0b, rW0b,
                                                   bl0, rb0, xb, pre, res);
    gather_bn_kernel<<<1024, 256, 0, stream>>>(off, ebuf, xb, pre, bnsum, bnsq);
    apply_bn_kernel<<<1024, 256, 0, stream>>>(pre, res, bnsum, bnsq, g0, be0, hbuf, hb);

    // ---- layer 1 ----
    hipMemsetAsync(bnsum, 0, 128 * sizeof(float), stream);
    proj_mfma_kernel<64><<<g12g, 256, 0, stream>>>(hb, Wl1b, Wr1b, nullptr,
                                                   bl1, nullptr, xb, pre, res);
    gather_bn_kernel<<<1024, 256, 0, stream>>>(off, ebuf, xb, pre, bnsum, bnsq);
    apply_bn_kernel<<<1024, 256, 0, stream>>>(pre, hbuf, bnsum, bnsq, g1, be1, hbuf, hb);

    // ---- layer 2 ----
    hipMemsetAsync(bnsum, 0, 128 * sizeof(float), stream);
    proj_mfma_kernel<64><<<g12g, 256, 0, stream>>>(hb, Wl2b, Wr2b, nullptr,
                                                   bl2, nullptr, xb, pre, res);
    gather_bn_kernel<<<1024, 256, 0, stream>>>(off, ebuf, xb, pre, bnsum, bnsq);
    apply_bn_kernel<<<1024, 256, 0, stream>>>(pre, hbuf, bnsum, bnsq, g2, be2, hbuf, hb);

    // ---- edge MLP (LDS-weight MFMA) ----
    edge_mlp_lds_kernel<<<EMG, 512, 0, stream>>>(hb, src, tgt, W1b, W2b, b1, b2, W3, b3, out);
}